// Round 4
// baseline (175.752 us; speedup 1.0000x reference)
//
#include <hip/hip_runtime.h>

#define NB 4
#define NC 6
#define NF 257
#define NT 2000
#define NG (NB * NF)        // 1028 (b,f) groups == grid size
#define NPAIR 15
#define NACC 74             // [0..5] s_diag, [6..11] n_diag, [12+4q..] s_re,s_im,n_re,n_im, [72] sum_ms, [73] sum_mn
#define BLK 256
#define NP2G (NT / 2)       // 1000 float2 per (b,f) group
#define NJ 4                // float2 bursts per thread (4*256 = 1024 >= 1000)
#define CS  (NF * NT)       // channel stride (floats)
#define CS2 (CS / 2)        // channel stride (float2)

typedef float nfloat4 __attribute__((ext_vector_type(4)));

// DPP row-shift-right add: lane i += lane (i-N) within its 16-lane row
// (0 beyond row edge). After shr8+shr4+shr2: lane14 = row evens-sum,
// lane15 = row odds-sum (HW-verified in prior session).
template<int CTRL>
__device__ __forceinline__ float dpp_add(float v) {
    int s = __builtin_amdgcn_update_dpp(0, __builtin_bit_cast(int, v), CTRL, 0xF, 0xF, true);
    return v + __builtin_bit_cast(float, s);
}

// upper-triangle pair index for c < e (enumeration matches PC/PE tables)
__device__ __forceinline__ int qidx(int c, int e) {
    return c * (2 * NC - 1 - c) / 2 + (e - c - 1);
}

struct P1Buf { float wms[2], wmn[2], rr[NC][2], ii[NC][2]; };  // 28 VGPR
struct P3Buf { float rr[NC][2], ii[NC][2]; };                  // 24 VGPR

// Phase-1 burst load for iteration J (J compile-time; J<3 always active)
#define P1_LOAD(BUF, J) do {                                                   \
    const int q0_ = (J) * BLK + tid;                                           \
    const bool act_ = ((J) < 3) || (q0_ < NP2G);                               \
    const int p_ = act_ ? q0_ : 0;                                             \
    { const float2 t0_ = m2s[p_]; BUF.wms[0] = t0_.x; BUF.wms[1] = t0_.y; }    \
    { const float2 t1_ = m2n[p_]; BUF.wmn[0] = t1_.x; BUF.wmn[1] = t1_.y; }    \
    _Pragma("unroll")                                                          \
    for (int c = 0; c < NC; c++) {                                             \
        const float2 tr_ = s2r[c * CS2 + p_];                                  \
        BUF.rr[c][0] = tr_.x; BUF.rr[c][1] = tr_.y;                            \
        const float2 ti_ = s2i[c * CS2 + p_];                                  \
        BUF.ii[c][0] = ti_.x; BUF.ii[c][1] = ti_.y;                            \
    }                                                                          \
    if (!act_) { BUF.wms[0] = BUF.wms[1] = BUF.wmn[0] = BUF.wmn[1] = 0.f; }    \
} while (0)

// Phase-1 accumulate from BUF into acc[]
#define P1_ACC(BUF) do {                                                       \
    _Pragma("unroll")                                                          \
    for (int k = 0; k < 2; k++) { acc[72] += BUF.wms[k]; acc[73] += BUF.wmn[k]; } \
    _Pragma("unroll")                                                          \
    for (int c = 0; c < NC; c++) {                                             \
        _Pragma("unroll")                                                      \
        for (int k = 0; k < 2; k++) {                                          \
            const float d_ = BUF.rr[c][k] * BUF.rr[c][k] + BUF.ii[c][k] * BUF.ii[c][k]; \
            acc[c]     += d_ * BUF.wms[k];                                     \
            acc[6 + c] += d_ * BUF.wmn[k];                                     \
        }                                                                      \
    }                                                                          \
    _Pragma("unroll")                                                          \
    for (int q = 0; q < NPAIR; q++) {                                          \
        const int c_ = PC[q], e_ = PE[q];                                      \
        _Pragma("unroll")                                                      \
        for (int k = 0; k < 2; k++) {                                          \
            const float cr_ = BUF.rr[c_][k] * BUF.rr[e_][k] + BUF.ii[c_][k] * BUF.ii[e_][k]; \
            const float ci_ = BUF.ii[c_][k] * BUF.rr[e_][k] - BUF.rr[c_][k] * BUF.ii[e_][k]; \
            acc[12 + 4 * q + 0] += cr_ * BUF.wms[k];                           \
            acc[12 + 4 * q + 1] += ci_ * BUF.wms[k];                           \
            acc[12 + 4 * q + 2] += cr_ * BUF.wmn[k];                           \
            acc[12 + 4 * q + 3] += ci_ * BUF.wmn[k];                           \
        }                                                                      \
    }                                                                          \
} while (0)

// Phase-3 burst load for iteration J
#define P3_LOAD(BUF, J) do {                                                   \
    const int q0_ = (J) * BLK + tid;                                           \
    const bool act_ = ((J) < 3) || (q0_ < NP2G);                               \
    const int p_ = act_ ? q0_ : 0;                                             \
    _Pragma("unroll")                                                          \
    for (int c = 0; c < NC; c++) {                                             \
        const float2 tr_ = s2r[c * CS2 + p_];                                  \
        BUF.rr[c][0] = tr_.x; BUF.rr[c][1] = tr_.y;                            \
        const float2 ti_ = s2i[c * CS2 + p_];                                  \
        BUF.ii[c][0] = ti_.x; BUF.ii[c][1] = ti_.y;                            \
    }                                                                          \
} while (0)

// Phase-3 apply + nontemporal store for iteration J
#define P3_APPLY(BUF, J) do {                                                  \
    const int q0_ = (J) * BLK + tid;                                           \
    const bool act_ = ((J) < 3) || (q0_ < NP2G);                               \
    float er_[2], ei_[2];                                                      \
    _Pragma("unroll")                                                          \
    for (int k = 0; k < 2; k++) {                                              \
        float a_ = 0.f, b_ = 0.f;                                              \
        _Pragma("unroll")                                                      \
        for (int c = 0; c < NC; c++) {                                         \
            a_ += wr[c] * BUF.rr[c][k] - wi[c] * BUF.ii[c][k];                 \
            b_ += wr[c] * BUF.ii[c][k] + wi[c] * BUF.rr[c][k];                 \
        }                                                                      \
        er_[k] = a_; ei_[k] = b_;                                              \
    }                                                                          \
    if (act_) {                                                                \
        nfloat4 o0_ = {er_[0], ei_[0], er_[1], ei_[1]};                        \
        __builtin_nontemporal_store(o0_, &o4[q0_]);                            \
    }                                                                          \
} while (0)

// ---------------- Fully fused MVDR, software-pipelined ---------------------
// One block per (b,f). Phase 1: 4 bursts, 2-deep pipelined (burst j+1 in
// flight while accumulating j). Phase 3's first two bursts are issued BEFORE
// the DPP reduce + LU so their HBM/L3 latency hides under phase 2 (T14).
__global__ __launch_bounds__(BLK) void mvdr_fused(
    const float* __restrict__ sr, const float* __restrict__ si,
    const float* __restrict__ ms, const float* __restrict__ mn,
    float* __restrict__ out)
{
    constexpr int PC[NPAIR] = {0,0,0,0,0,1,1,1,1,2,2,2,3,3,4};
    constexpr int PE[NPAIR] = {1,2,3,4,5,2,3,4,5,3,4,5,4,5,5};

    const int g  = blockIdx.x;
    const int b  = g / NF;
    const int f  = g - b * NF;
    const int sbase = b * NC * CS + f * NT;
    const int tid = threadIdx.x;

    const float2* s2r = (const float2*)(sr + sbase);
    const float2* s2i = (const float2*)(si + sbase);
    const float2* m2s = (const float2*)(ms + g * NT);
    const float2* m2n = (const float2*)(mn + g * NT);

    float acc[NACC];
    #pragma unroll
    for (int i = 0; i < NACC; i++) acc[i] = 0.f;

    // ---------------- Phase 1: pipelined accumulation ----------------------
    {
        P1Buf A, B;
        P1_LOAD(A, 0);
        P1_LOAD(B, 1);      // two bursts in flight
        P1_ACC(A);
        P1_LOAD(A, 2);
        P1_ACC(B);
        P1_LOAD(B, 3);
        P1_ACC(A);
        P1_ACC(B);
    }

    // Pre-issue phase 3's first two spec bursts: their latency hides under
    // the DPP reduce + LDS + LU below.
    P3Buf PA, PB;
    P3_LOAD(PA, 0);
    P3_LOAD(PB, 1);

    // ---------------- Phase 2: block reduction of the 74 accumulators ------
    #pragma unroll
    for (int i = 0; i < NACC; i++) {
        float v = acc[i];
        v = dpp_add<0x118>(v);   // row_shr:8
        v = dpp_add<0x114>(v);   // row_shr:4
        v = dpp_add<0x112>(v);   // row_shr:2
        acc[i] = v;
    }

    __shared__ float red[32][NACC];
    __shared__ float fin[NACC];
    __shared__ float sdr[NC], sdi[NC];
    __shared__ float wsh[2 * NC];

    const int lane16 = tid & 15;
    const int ridx   = ((tid >> 4) << 1) | (lane16 & 1);  // 0..31
    if (lane16 >= 14) {
        #pragma unroll
        for (int i = 0; i < NACC; i++) red[ridx][i] = acc[i];
    }
    __syncthreads();

    if (tid < NACC) {
        float s = 0.f;
        #pragma unroll
        for (int r = 0; r < 32; r++) s += red[r][tid];
        fin[tid] = s;
    }
    __syncthreads();

    // ---------------- Phase 2c: in-block solve (lanes 0..5) ----------------
    float xr[NC], xi[NC];
    if (tid < NC) {
        const float invS = 1.f / (fin[72] + 1e-15f);
        const float invN = 1.f / (fin[73] + 1e-15f);

        // A = normalized psd_n + eps*I
        float Ar[NC][NC], Ai[NC][NC];
        #pragma unroll
        for (int c = 0; c < NC; c++) { Ar[c][c] = fin[6 + c] * invN; Ai[c][c] = 0.f; }
        #pragma unroll
        for (int q = 0; q < NPAIR; q++) {
            const int c = PC[q], e = PE[q];
            const float nre = fin[12 + 4 * q + 2] * invN;
            const float nim = fin[12 + 4 * q + 3] * invN;
            Ar[c][e] = nre;  Ai[c][e] = nim;
            Ar[e][c] = nre;  Ai[e][c] = -nim;
        }
        {
            float trn = 0.f;
            #pragma unroll
            for (int c = 0; c < NC; c++) trn += Ar[c][c];
            const float eps = trn * 1e-7f + 1e-8f;
            #pragma unroll
            for (int c = 0; c < NC; c++) Ar[c][c] += eps;
        }

        // In-place unpivoted LU (redundant on each of the 6 lanes)
        #pragma unroll
        for (int k = 0; k < NC; k++) {
            const float dr = Ar[k][k], di = Ai[k][k];
            const float idn = 1.f / (dr * dr + di * di);
            const float pr = dr * idn, pi = -di * idn;
            #pragma unroll
            for (int i = k + 1; i < NC; i++) {
                const float lr = Ar[i][k] * pr - Ai[i][k] * pi;
                const float li = Ar[i][k] * pi + Ai[i][k] * pr;
                Ar[i][k] = lr; Ai[i][k] = li;
                #pragma unroll
                for (int j = k + 1; j < NC; j++) {
                    Ar[i][j] -= lr * Ar[k][j] - li * Ai[k][j];
                    Ai[i][j] -= lr * Ai[k][j] + li * Ar[k][j];
                }
            }
        }

        // RHS = column `tid` of normalized psd_s (i compile-time, tid runtime)
        #pragma unroll
        for (int i = 0; i < NC; i++) {
            if (i == tid)      { xr[i] = fin[i] * invS;  xi[i] = 0.f; }
            else if (i < tid)  { const int q = qidx(i, tid);
                                 xr[i] = fin[12 + 4 * q] * invS;  xi[i] =  fin[13 + 4 * q] * invS; }
            else               { const int q = qidx(tid, i);
                                 xr[i] = fin[12 + 4 * q] * invS;  xi[i] = -fin[13 + 4 * q] * invS; }
        }
        // forward substitution
        #pragma unroll
        for (int i = 1; i < NC; i++) {
            #pragma unroll
            for (int k = 0; k < NC - 1; k++) if (k < i) {
                xr[i] -= Ar[i][k] * xr[k] - Ai[i][k] * xi[k];
                xi[i] -= Ar[i][k] * xi[k] + Ai[i][k] * xr[k];
            }
        }
        // backward substitution
        #pragma unroll
        for (int i = NC - 1; i >= 0; i--) {
            #pragma unroll
            for (int k = 0; k < NC; k++) if (k > i) {
                xr[i] -= Ar[i][k] * xr[k] - Ai[i][k] * xi[k];
                xi[i] -= Ar[i][k] * xi[k] + Ai[i][k] * xr[k];
            }
            const float dr = Ar[i][i], di = Ai[i][i];
            const float idn = 1.f / (dr * dr + di * di);
            const float pr = dr * idn, pi = -di * idn;
            const float t0 = xr[i] * pr - xi[i] * pi;
            xi[i] = xr[i] * pi + xi[i] * pr;
            xr[i] = t0;
        }
        // own diagonal element, extracted without runtime register indexing
        float dgr = xr[0], dgi = xi[0];
        #pragma unroll
        for (int i = 1; i < NC; i++) if (tid == i) { dgr = xr[i]; dgi = xi[i]; }
        sdr[tid] = dgr; sdi[tid] = dgi;
    }
    __syncthreads();

    if (tid == 0) {
        float trr = 1e-8f, tri = 0.f;   // TIK_EPS on real part of trace
        #pragma unroll
        for (int c = 0; c < NC; c++) { trr += sdr[c]; tri += sdi[c]; }
        const float idn = 1.f / (trr * trr + tri * tri);
        #pragma unroll
        for (int c = 0; c < NC; c++) {
            // lane 0's xr/xi == column 0 of the numerator (persists across barrier)
            const float wre = (xr[c] * trr + xi[c] * tri) * idn;
            const float wim = (xi[c] * trr - xr[c] * tri) * idn;
            wsh[c]     = wre;    // conj(w): real
            wsh[6 + c] = -wim;   // conj(w): imag
        }
    }
    __syncthreads();

    // ---------------- Phase 3: pipelined apply (bursts 0,1 already in flight)
    float wr[NC], wi[NC];
    #pragma unroll
    for (int c = 0; c < NC; c++) { wr[c] = wsh[c]; wi[c] = wsh[6 + c]; }

    nfloat4* o4 = (nfloat4*)(out + 2 * g * NT);

    P3_APPLY(PA, 0);
    P3_LOAD(PA, 2);
    P3_APPLY(PB, 1);
    P3_LOAD(PB, 3);
    P3_APPLY(PA, 2);
    P3_APPLY(PB, 3);
}

extern "C" void kernel_launch(void* const* d_in, const int* in_sizes, int n_in,
                              void* d_out, int out_size, void* d_ws, size_t ws_size,
                              hipStream_t stream) {
    const float* sr = (const float*)d_in[0];
    const float* si = (const float*)d_in[1];
    const float* ms = (const float*)d_in[2];
    const float* mn = (const float*)d_in[3];
    float* out = (float*)d_out;
    (void)d_ws; (void)ws_size;   // workspace unused

    mvdr_fused<<<NG, BLK, 0, stream>>>(sr, si, ms, mn, out);
}

// Round 5
// 173.247 us; speedup vs baseline: 1.0145x; 1.0145x over previous
//
#include <hip/hip_runtime.h>

#define NB 4
#define NC 6
#define NF 257
#define NT 2000
#define NG (NB * NF)        // 1028 (b,f) groups
#define NPAIR 15
#define NACC 74             // [0..5] s_diag, [6..11] n_diag, [12+4q..] s_re,s_im,n_re,n_im, [72] sum_ms, [73] sum_mn
#define NCHUNK 2
#define TCH (NT / NCHUNK)   // 1000 t per chunk
#define NP4 (TCH / 4)       // 250 float4 positions per chunk
#define BLK 256
#define CS  (NF * NT)       // channel stride (floats)
#define CS4 (CS / 4)        // channel stride (float4)

typedef float nfloat4 __attribute__((ext_vector_type(4)));

// DPP row-shift-right add: lane i += lane (i-N) within its 16-lane row
// (0 beyond row edge). After shr8+shr4+shr2: lane14 = row evens-sum,
// lane15 = row odds-sum (HW-verified in prior session).
template<int CTRL>
__device__ __forceinline__ float dpp_add(float v) {
    int s = __builtin_amdgcn_update_dpp(0, __builtin_bit_cast(int, v), CTRL, 0xF, 0xF, true);
    return v + __builtin_bit_cast(float, s);
}

// ---------------- Kernel A: raw weighted PSD partials per (group, chunk) ----
// Round-0 structure, VECTORIZED: dwordx4 loads (16 B/lane — the measured
// coalescing sweet spot) instead of dwordx2. 2056 blocks x 256 threads,
// each thread owns 4 consecutive t (one float4 per stream, 14-load burst).
// No VGPR cap (two-arg launch_bounds caused the earlier spill disasters).
__global__ __launch_bounds__(BLK) void psd_kernel(
    const float* __restrict__ sr, const float* __restrict__ si,
    const float* __restrict__ ms, const float* __restrict__ mn,
    float* __restrict__ wsp)
{
    constexpr int PC[NPAIR] = {0,0,0,0,0,1,1,1,1,2,2,2,3,3,4};
    constexpr int PE[NPAIR] = {1,2,3,4,5,2,3,4,5,3,4,5,4,5,5};

    const int bx = blockIdx.x;
    const int g  = bx >> 1;
    const int b  = g / NF;
    const int f  = g - b * NF;
    const int tb = (bx & 1) * TCH;
    const int sbase = b * NC * CS + f * NT + tb;   // % 4 == 0
    const int mbase = g * NT + tb;                 // % 4 == 0

    const nfloat4* s4r = (const nfloat4*)(sr + sbase);
    const nfloat4* s4i = (const nfloat4*)(si + sbase);
    const nfloat4* m4s = (const nfloat4*)(ms + mbase);
    const nfloat4* m4n = (const nfloat4*)(mn + mbase);

    float acc[NACC];
    #pragma unroll
    for (int i = 0; i < NACC; i++) acc[i] = 0.f;

    // Unconditional load burst; inactive lanes load p=0 and zero their mask
    // weights (every accumulator term carries a mask factor -> contributes 0).
    const bool act = threadIdx.x < NP4;
    const int  p   = act ? threadIdx.x : 0;
    {
        float wms[4], wmn[4], rr[NC][4], ii[NC][4];
        {
            const nfloat4 t0 = m4s[p];
            wms[0] = t0.x; wms[1] = t0.y; wms[2] = t0.z; wms[3] = t0.w;
            const nfloat4 t1 = m4n[p];
            wmn[0] = t1.x; wmn[1] = t1.y; wmn[2] = t1.z; wmn[3] = t1.w;
        }
        #pragma unroll
        for (int c = 0; c < NC; c++) {
            const nfloat4 tr = s4r[c * CS4 + p];
            rr[c][0] = tr.x; rr[c][1] = tr.y; rr[c][2] = tr.z; rr[c][3] = tr.w;
            const nfloat4 ti = s4i[c * CS4 + p];
            ii[c][0] = ti.x; ii[c][1] = ti.y; ii[c][2] = ti.z; ii[c][3] = ti.w;
        }
        if (!act) {
            #pragma unroll
            for (int k = 0; k < 4; k++) { wms[k] = 0.f; wmn[k] = 0.f; }
        }
        #pragma unroll
        for (int k = 0; k < 4; k++) { acc[72] += wms[k]; acc[73] += wmn[k]; }
        #pragma unroll
        for (int c = 0; c < NC; c++) {
            #pragma unroll
            for (int k = 0; k < 4; k++) {
                const float d = rr[c][k] * rr[c][k] + ii[c][k] * ii[c][k];
                acc[c]     += d * wms[k];
                acc[6 + c] += d * wmn[k];
            }
        }
        #pragma unroll
        for (int q = 0; q < NPAIR; q++) {
            const int c = PC[q], e = PE[q];
            #pragma unroll
            for (int k = 0; k < 4; k++) {
                const float cr = rr[c][k] * rr[e][k] + ii[c][k] * ii[e][k];
                const float ci = ii[c][k] * rr[e][k] - rr[c][k] * ii[e][k];
                acc[12 + 4 * q + 0] += cr * wms[k];
                acc[12 + 4 * q + 1] += ci * wms[k];
                acc[12 + 4 * q + 2] += cr * wmn[k];
                acc[12 + 4 * q + 3] += ci * wmn[k];
            }
        }
    }

    // In-row DPP reduction (VALU pipe): lane14 = row evens-sum, lane15 = odds.
    #pragma unroll
    for (int i = 0; i < NACC; i++) {
        float v = acc[i];
        v = dpp_add<0x118>(v);   // row_shr:8
        v = dpp_add<0x114>(v);   // row_shr:4
        v = dpp_add<0x112>(v);   // row_shr:2
        acc[i] = v;
    }

    __shared__ float red[32][NACC];
    const int lane16 = threadIdx.x & 15;
    const int ridx   = ((threadIdx.x >> 4) << 1) | (lane16 & 1);  // 0..31
    if (lane16 >= 14) {
        #pragma unroll
        for (int i = 0; i < NACC; i++) red[ridx][i] = acc[i];
    }
    __syncthreads();

    if (threadIdx.x < NACC) {
        float s = 0.f;
        #pragma unroll
        for (int r = 0; r < 32; r++) s += red[r][threadIdx.x];
        wsp[bx * NACC + threadIdx.x] = s;
    }
}

// ---------------- Kernel B: one thread per (b,f) — LU + column solves -------
// Verbatim round-0 verified solve; only the partial-row sum changed (2 rows).
// launch_bounds(64,1): high VGPR allowed so nothing spills.
__global__ __launch_bounds__(64, 1) void solve_kernel(
    const float* __restrict__ wsp, float* __restrict__ wsw)
{
    const int gid = blockIdx.x * 64 + threadIdx.x;
    if (gid >= NG) return;

    constexpr int PC[NPAIR] = {0,0,0,0,0,1,1,1,1,2,2,2,3,3,4};
    constexpr int PE[NPAIR] = {1,2,3,4,5,2,3,4,5,3,4,5,4,5,5};
    constexpr int QIDX[NC][NC] = {
        {-1, 0, 1, 2, 3, 4},
        {-1,-1, 5, 6, 7, 8},
        {-1,-1,-1, 9,10,11},
        {-1,-1,-1,-1,12,13},
        {-1,-1,-1,-1,-1,14},
        {-1,-1,-1,-1,-1,-1}};

    const float* p0 = wsp + (NCHUNK * gid) * NACC;
    float fin[NACC];
    #pragma unroll
    for (int i = 0; i < NACC; i++)
        fin[i] = p0[i] + p0[NACC + i];

    const float invS = 1.f / (fin[72] + 1e-15f);
    const float invN = 1.f / (fin[73] + 1e-15f);

    // A = normalized psd_n + eps*I
    float Ar[NC][NC], Ai[NC][NC];
    #pragma unroll
    for (int c = 0; c < NC; c++) { Ar[c][c] = fin[6 + c] * invN; Ai[c][c] = 0.f; }
    #pragma unroll
    for (int q = 0; q < NPAIR; q++) {
        const int c = PC[q], e = PE[q];
        const float nre = fin[12 + 4 * q + 2] * invN;
        const float nim = fin[12 + 4 * q + 3] * invN;
        Ar[c][e] = nre;  Ai[c][e] = nim;
        Ar[e][c] = nre;  Ai[e][c] = -nim;
    }
    {
        float trn = 0.f;
        #pragma unroll
        for (int c = 0; c < NC; c++) trn += Ar[c][c];
        const float eps = trn * 1e-7f + 1e-8f;
        #pragma unroll
        for (int c = 0; c < NC; c++) Ar[c][c] += eps;
    }

    // In-place unpivoted LU: L (unit diag) below, U on/above.
    #pragma unroll
    for (int k = 0; k < NC; k++) {
        const float dr = Ar[k][k], di = Ai[k][k];
        const float idn = 1.f / (dr * dr + di * di);
        const float pr = dr * idn, pi = -di * idn;
        #pragma unroll
        for (int i = k + 1; i < NC; i++) {
            const float lr = Ar[i][k] * pr - Ai[i][k] * pi;
            const float li = Ar[i][k] * pi + Ai[i][k] * pr;
            Ar[i][k] = lr; Ai[i][k] = li;
            #pragma unroll
            for (int j = k + 1; j < NC; j++) {
                Ar[i][j] -= lr * Ar[k][j] - li * Ai[k][j];
                Ai[i][j] -= lr * Ai[k][j] + li * Ar[k][j];
            }
        }
    }

    // Column-by-column solve of A x = b_j (b_j = col j of normalized psd_s).
    float trr = 1e-8f, tri = 0.f;   // TIK_EPS on real part of trace
    float w0r[NC], w0i[NC];
    #pragma unroll
    for (int j = 0; j < NC; j++) {
        float xr[NC], xi[NC];
        #pragma unroll
        for (int i = 0; i < NC; i++) {
            if (i == j)      { xr[i] = fin[j] * invS;                      xi[i] = 0.f; }
            else if (i < j)  { const int q = QIDX[i][j];
                               xr[i] = fin[12 + 4 * q] * invS;  xi[i] =  fin[13 + 4 * q] * invS; }
            else             { const int q = QIDX[j][i];
                               xr[i] = fin[12 + 4 * q] * invS;  xi[i] = -fin[13 + 4 * q] * invS; }
        }
        #pragma unroll
        for (int i = 1; i < NC; i++) {
            #pragma unroll
            for (int k = 0; k < NC - 1; k++) if (k < i) {
                xr[i] -= Ar[i][k] * xr[k] - Ai[i][k] * xi[k];
                xi[i] -= Ar[i][k] * xi[k] + Ai[i][k] * xr[k];
            }
        }
        #pragma unroll
        for (int i = NC - 1; i >= 0; i--) {
            #pragma unroll
            for (int k = 0; k < NC; k++) if (k > i) {
                xr[i] -= Ar[i][k] * xr[k] - Ai[i][k] * xi[k];
                xi[i] -= Ar[i][k] * xi[k] + Ai[i][k] * xr[k];
            }
            const float dr = Ar[i][i], di = Ai[i][i];
            const float idn = 1.f / (dr * dr + di * di);
            const float pr = dr * idn, pi = -di * idn;
            const float tr0 = xr[i] * pr - xi[i] * pi;
            xi[i] = xr[i] * pi + xi[i] * pr;
            xr[i] = tr0;
        }
        trr += xr[j]; tri += xi[j];
        if (j == 0) {
            #pragma unroll
            for (int i = 0; i < NC; i++) { w0r[i] = xr[i]; w0i[i] = xi[i]; }
        }
    }

    const float idn = 1.f / (trr * trr + tri * tri);
    #pragma unroll
    for (int c = 0; c < NC; c++) {
        const float wre = (w0r[c] * trr + w0i[c] * tri) * idn;
        const float wim = (w0i[c] * trr - w0r[c] * tri) * idn;
        wsw[gid * 12 + c]     = wre;    // conj(w): real
        wsw[gid * 12 + 6 + c] = -wim;   // conj(w): imag
    }
}

// ---------------- Kernel C: enh[t] = sum_c conj(w[c]) * spec[c,t] -----------
// Vectorized: 12 dwordx4 loads covering 4 t per thread, 2 nontemporal
// dwordx4 stores. 2056 blocks x 256 threads.
__global__ __launch_bounds__(BLK) void apply_kernel(
    const float* __restrict__ sr, const float* __restrict__ si,
    const float* __restrict__ wsw, float* __restrict__ out)
{
    const int bx = blockIdx.x;
    const int g  = bx >> 1;
    const int b  = g / NF;
    const int f  = g - b * NF;
    const int tb = (bx & 1) * TCH;
    const int sbase = b * NC * CS + f * NT + tb;

    const nfloat4* s4r = (const nfloat4*)(sr + sbase);
    const nfloat4* s4i = (const nfloat4*)(si + sbase);

    float wr[NC], wi[NC];
    #pragma unroll
    for (int c = 0; c < NC; c++) {
        wr[c] = wsw[g * 12 + c];
        wi[c] = wsw[g * 12 + 6 + c];
    }

    nfloat4* o4 = (nfloat4*)(out + 2 * (g * NT + tb));

    const int p = threadIdx.x;
    if (p < NP4) {
        float rr[NC][4], ii[NC][4];
        #pragma unroll
        for (int c = 0; c < NC; c++) {
            const nfloat4 tr = s4r[c * CS4 + p];
            rr[c][0] = tr.x; rr[c][1] = tr.y; rr[c][2] = tr.z; rr[c][3] = tr.w;
            const nfloat4 ti = s4i[c * CS4 + p];
            ii[c][0] = ti.x; ii[c][1] = ti.y; ii[c][2] = ti.z; ii[c][3] = ti.w;
        }
        float er[4], ei[4];
        #pragma unroll
        for (int k = 0; k < 4; k++) {
            float a = 0.f, bb = 0.f;
            #pragma unroll
            for (int c = 0; c < NC; c++) {
                a  += wr[c] * rr[c][k] - wi[c] * ii[c][k];
                bb += wr[c] * ii[c][k] + wi[c] * rr[c][k];
            }
            er[k] = a; ei[k] = bb;
        }
        nfloat4 o0 = {er[0], ei[0], er[1], ei[1]};
        nfloat4 o1 = {er[2], ei[2], er[3], ei[3]};
        __builtin_nontemporal_store(o0, &o4[2 * p]);
        __builtin_nontemporal_store(o1, &o4[2 * p + 1]);
    }
}

extern "C" void kernel_launch(void* const* d_in, const int* in_sizes, int n_in,
                              void* d_out, int out_size, void* d_ws, size_t ws_size,
                              hipStream_t stream) {
    const float* sr = (const float*)d_in[0];
    const float* si = (const float*)d_in[1];
    const float* ms = (const float*)d_in[2];
    const float* mn = (const float*)d_in[3];
    float* out = (float*)d_out;

    float* wsp = (float*)d_ws;                       // [NG*NCHUNK][NACC] partials
    float* wsw = wsp + NG * NCHUNK * NACC;           // [NG][12] conj(w)

    psd_kernel<<<NG * NCHUNK, BLK, 0, stream>>>(sr, si, ms, mn, wsp);
    solve_kernel<<<(NG + 63) / 64, 64, 0, stream>>>(wsp, wsw);
    apply_kernel<<<NG * NCHUNK, BLK, 0, stream>>>(sr, si, wsw, out);
}